// Round 8
// baseline (429.265 us; speedup 1.0000x reference)
//
#include <hip/hip_runtime.h>
#include <hip/hip_bf16.h>
#include <stdint.h>
#include <math.h>

#define NS 2048
#define DD 64
#define HH 256

struct SubKeys { uint32_t a[DD]; uint32_t b[DD]; };

// JAX/Random123 threefry2x32, 20 rounds.
__host__ __device__ static inline void tf2x32(uint32_t k0, uint32_t k1,
                                              uint32_t x0, uint32_t x1,
                                              uint32_t* o0, uint32_t* o1) {
  uint32_t ks0 = k0, ks1 = k1, ks2 = k0 ^ k1 ^ 0x1BD11BDAu;
  x0 += ks0; x1 += ks1;
#define TFROT(r) { x0 += x1; x1 = (x1 << (r)) | (x1 >> (32 - (r))); x1 ^= x0; }
  TFROT(13) TFROT(15) TFROT(26) TFROT(6)  x0 += ks1; x1 += ks2 + 1u;
  TFROT(17) TFROT(29) TFROT(16) TFROT(24) x0 += ks2; x1 += ks0 + 2u;
  TFROT(13) TFROT(15) TFROT(26) TFROT(6)  x0 += ks0; x1 += ks1 + 3u;
  TFROT(17) TFROT(29) TFROT(16) TFROT(24) x0 += ks1; x1 += ks2 + 4u;
  TFROT(13) TFROT(15) TFROT(26) TFROT(6)  x0 += ks2; x1 += ks0 + 5u;
#undef TFROT
  *o0 = x0; *o1 = x1;
}

__launch_bounds__(HH)
__global__ void QNADE_43473658970605_kernel(const float* __restrict__ W1,
                                            const float* __restrict__ b1,
                                            const float* __restrict__ W2,
                                            const float* __restrict__ b2,
                                            float* __restrict__ out,
                                            SubKeys sk) {
  __shared__ float  dZ1L[DD][HH + 1];   // f32 dz1 tile for Phase B
  __shared__ float  uL[DD];
  __shared__ float  xrL[DD];
  __shared__ double redd[2][4][2];      // f64 cross-wave reduction buffer

  const int tid  = threadIdx.x;      // = hidden unit h
  const int i    = blockIdx.x;       // = sample index
  const int lane = tid & 63;
  const int wv   = tid >> 6;

  // Per-step uniforms, JAX partitionable threefry counter-mode:
  // bits[i] = o0 ^ o1 of threefry2x32(subkey_d, (hi=0, lo=i)).
  if (tid < DD) {
    uint32_t o0, o1;
    tf2x32(sk.a[tid], sk.b[tid], 0u, (uint32_t)i, &o0, &o1);
    uint32_t r = o0 ^ o1;
    uL[tid] = __uint_as_float(0x3f800000u | (r >> 9)) - 1.0f;  // exact
  }

  const double b1h = (double)b1[tid];
  const double w20 = (double)W2[tid];
  const double w21 = (double)W2[HH + tid];
  const double b20 = (double)b2[0], b21 = (double)b2[1];
  const float* __restrict__ w1row = W1 + (size_t)tid * DD;

  double z1 = b1h;
  double wav = 1.0;
  double gw2_0 = 0., gw2_1 = 0., gb2_0 = 0., gb2_1 = 0.;

  __syncthreads();

  // -------- Phase A: full f64 forward + backward-local (np-faithful decisions) -----
  for (int d = 0; d < DD; ++d) {
    double hcur = tanh(z1);
    double p0 = hcur * w20;
    double p1 = hcur * w21;
    #pragma unroll
    for (int m = 32; m >= 1; m >>= 1) {   // 64-lane f64 butterfly reduce
      p0 += __shfl_xor(p0, m, 64);
      p1 += __shfl_xor(p1, m, 64);
    }
    const int par = d & 1;
    if (lane == 0) { redd[par][wv][0] = p0; redd[par][wv][1] = p1; }
    __syncthreads();
    double s0 = redd[par][0][0] + redd[par][1][0] + redd[par][2][0] + redd[par][3][0] + b20;
    double s1 = redd[par][0][1] + redd[par][1][1] + redd[par][2][1] + redd[par][3][1] + b21;

    double nrm   = sqrt(s0 * s0 + s1 * s1);
    double psi_p = s0 / nrm;
    double psi_n = s1 / nrm;
    double p     = fmin(psi_p * psi_p, 1.0);   // clip(psi^2, 0, 1)

    bool   bit   = (double)uL[d] < p;          // u value exact in f32/f64
    double spin  = bit ? 1.0 : -1.0;
    double sel   = bit ? psi_p : psi_n;
    wav *= sel;

    double g = 1.0 / sel;
    double dz2_0 = ((bit ? g : 0.0) - psi_p) / nrm;
    double dz2_1 = ((bit ? 0.0 : g) - psi_n) / nrm;

    gw2_0 += dz2_0 * hcur;  gw2_1 += dz2_1 * hcur;
    gb2_0 += dz2_0;         gb2_1 += dz2_1;

    double dh  = dz2_0 * w20 + dz2_1 * w21;
    double dz1 = dh * (1.0 - hcur * hcur);
    dZ1L[d][tid] = (float)dz1;
    if (tid == 0) xrL[d] = (float)spin;

    z1 = fma(spin, (double)w1row[d], z1);   // f64 ascending signed accumulation
  }

  // ---------------- Output offsets (flat concat: WAV, x, gW1, gb1, gW2, gb2) --------
  const size_t XO  = (size_t)NS;                       // 2048
  const size_t GW1 = XO  + (size_t)NS * DD;            // 133120
  const size_t GB1 = GW1 + (size_t)NS * HH * DD;       // 33687552
  const size_t GW2 = GB1 + (size_t)NS * HH;            // 34211840
  const size_t GB2 = GW2 + (size_t)NS * 2 * HH;        // 35260416

  out[GW2 + (size_t)i * 2 * HH + tid]      = (float)gw2_0;
  out[GW2 + (size_t)i * 2 * HH + HH + tid] = (float)gw2_1;
  if (tid == 0) {
    out[i] = (float)wav;
    out[GB2 + (size_t)i * 2 + 0] = (float)gb2_0;
    out[GB2 + (size_t)i * 2 + 1] = (float)gb2_1;
  }

  __syncthreads();
  if (tid < DD) out[XO + (size_t)i * DD + tid] = xrL[tid];

  // ------- Phase B: serial per-thread suffix.  gW1[h,j] = x_j * sum_{d>j} dz1[d,h] --
  const size_t baseW1 = GW1 + (size_t)i * (HH * DD) + (size_t)tid * DD;
  float suf = 0.0f;
  #pragma unroll
  for (int j = DD - 1; j >= 0; --j) {
    out[baseW1 + j] = xrL[j] * suf;   // suffix EXCLUSIVE of j (mask is j < d)
    suf += dZ1L[j][tid];              // col-read, stride 257 -> 2-way banked, free
  }
  out[GB1 + (size_t)i * HH + tid] = suf;  // gb1
}

extern "C" void kernel_launch(void* const* d_in, const int* in_sizes, int n_in,
                              void* d_out, int out_size, void* d_ws, size_t ws_size,
                              hipStream_t stream) {
  (void)in_sizes; (void)n_in; (void)out_size; (void)d_ws; (void)ws_size;
  const float* W1 = (const float*)d_in[0];
  const float* b1 = (const float*)d_in[1];
  const float* W2 = (const float*)d_in[2];
  const float* b2 = (const float*)d_in[3];
  float* out = (float*)d_out;

  // Host-side JAX key chain, PARTITIONABLE threefry split:
  // key(1) = (0,1). split(key): child i = threefry2x32(key, (0, i)) -> (o0, o1).
  // key, sub = split(key) -> key = child 0, sub = child 1.
  SubKeys sk;
  uint32_t k0 = 0u, k1 = 1u;
  for (int d = 0; d < DD; ++d) {
    uint32_t n0, n1, s0, s1;
    tf2x32(k0, k1, 0u, 0u, &n0, &n1);   // child 0 -> next carry key
    tf2x32(k0, k1, 0u, 1u, &s0, &s1);   // child 1 -> sub key
    sk.a[d] = s0; sk.b[d] = s1;
    k0 = n0; k1 = n1;
  }

  QNADE_43473658970605_kernel<<<dim3(NS), dim3(HH), 0, stream>>>(W1, b1, W2, b2, out, sk);
}

// Round 9
// 229.490 us; speedup vs baseline: 1.8705x; 1.8705x over previous
//
#include <hip/hip_runtime.h>
#include <hip/hip_bf16.h>
#include <stdint.h>
#include <math.h>

#define NS 2048
#define DD 64
#define HH 256

struct SubKeys { uint32_t a[DD]; uint32_t b[DD]; };

// JAX/Random123 threefry2x32, 20 rounds.
__host__ __device__ static inline void tf2x32(uint32_t k0, uint32_t k1,
                                              uint32_t x0, uint32_t x1,
                                              uint32_t* o0, uint32_t* o1) {
  uint32_t ks0 = k0, ks1 = k1, ks2 = k0 ^ k1 ^ 0x1BD11BDAu;
  x0 += ks0; x1 += ks1;
#define TFROT(r) { x0 += x1; x1 = (x1 << (r)) | (x1 >> (32 - (r))); x1 ^= x0; }
  TFROT(13) TFROT(15) TFROT(26) TFROT(6)  x0 += ks1; x1 += ks2 + 1u;
  TFROT(17) TFROT(29) TFROT(16) TFROT(24) x0 += ks2; x1 += ks0 + 2u;
  TFROT(13) TFROT(15) TFROT(26) TFROT(6)  x0 += ks0; x1 += ks1 + 3u;
  TFROT(17) TFROT(29) TFROT(16) TFROT(24) x0 += ks1; x1 += ks2 + 4u;
  TFROT(13) TFROT(15) TFROT(26) TFROT(6)  x0 += ks2; x1 += ks0 + 5u;
#undef TFROT
  *o0 = x0; *o1 = x1;
}

__launch_bounds__(HH, 4)   // cap VGPR at 128 -> 4 waves/SIMD (16 waves/CU)
__global__ void QNADE_43473658970605_kernel(const float* __restrict__ W1,
                                            const float* __restrict__ b1,
                                            const float* __restrict__ W2,
                                            const float* __restrict__ b2,
                                            float* __restrict__ out,
                                            SubKeys sk) {
  __shared__ float  uL[DD];           // per-step uniforms
  __shared__ float  xrL[DD];          // spins
  __shared__ float  dz20L[DD];        // block-uniform dZ2 components per step
  __shared__ float  dz21L[DD];
  __shared__ double redd[2][4][2];    // f64 cross-wave reduction (parity dbuf)
  __shared__ float  tbuf[4][16][66];  // per-wave transpose buffer for gW1 stores

  const int tid  = threadIdx.x;      // = hidden unit h
  const int i    = blockIdx.x;       // = sample index
  const int lane = tid & 63;
  const int wv   = tid >> 6;

  // Per-step uniforms, JAX partitionable threefry counter-mode:
  // bits[i] = o0 ^ o1 of threefry2x32(subkey_d, (hi=0, lo=i)).
  if (tid < DD) {
    uint32_t o0, o1;
    tf2x32(sk.a[tid], sk.b[tid], 0u, (uint32_t)i, &o0, &o1);
    uint32_t r = o0 ^ o1;
    uL[tid] = __uint_as_float(0x3f800000u | (r >> 9)) - 1.0f;  // exact
  }

  const float  b1f  = b1[tid];
  const float  w20f = W2[tid];
  const float  w21f = W2[HH + tid];
  const double w20d = (double)w20f, w21d = (double)w21f;
  const double b20d = (double)b2[0], b21d = (double)b2[1];
  const float* __restrict__ w1row = W1 + (size_t)tid * DD;

  double z1  = (double)b1f;          // decision-critical accumulator stays f64
  float  wav = 1.0f;
  float  gw20 = 0.f, gw21 = 0.f, gb20 = 0.f, gb21 = 0.f, gb1f = 0.f;

  __syncthreads();

  // -------- Phase A: forward (f64 spine, f32 tanh) + f32 backward-local ------------
  #pragma unroll 2
  for (int d = 0; d < DD; ++d) {
    float  hf = tanhf((float)z1);           // f32 tanh: eta ~1e-7 << np's own noise
    double hd = (double)hf;
    double p0 = hd * w20d;
    double p1 = hd * w21d;
    #pragma unroll
    for (int m = 32; m >= 1; m >>= 1) {     // 64-lane f64 butterfly
      p0 += __shfl_xor(p0, m, 64);
      p1 += __shfl_xor(p1, m, 64);
    }
    const int par = d & 1;
    if (lane == 0) { redd[par][wv][0] = p0; redd[par][wv][1] = p1; }
    __syncthreads();
    double s0 = redd[par][0][0] + redd[par][1][0] + redd[par][2][0] + redd[par][3][0] + b20d;
    double s1 = redd[par][0][1] + redd[par][1][1] + redd[par][2][1] + redd[par][3][1] + b21d;

    double ss = s0 * s0 + s1 * s1;
    double pd = fmin(s0 * s0 / ss, 1.0);    // p = psi_p^2, no sqrt needed
    bool   bit = (double)uL[d] < pd;        // f64 decision, np-faithful
    float  spinf = bit ? 1.0f : -1.0f;

    // backward-local entirely in f32 (does not feed decisions)
    float s0f = (float)s0, s1f = (float)s1;
    float nrmf = sqrtf(s0f * s0f + s1f * s1f);
    float psip = s0f / nrmf, psin = s1f / nrmf;
    float self = bit ? psip : psin;
    wav *= self;
    float gf = 1.0f / self;
    float dz20 = ((bit ? gf : 0.0f) - psip) / nrmf;
    float dz21 = ((bit ? 0.0f : gf) - psin) / nrmf;
    gw20 += dz20 * hf;  gw21 += dz21 * hf;
    gb20 += dz20;       gb21 += dz21;
    float dz1f = (dz20 * w20f + dz21 * w21f) * (1.0f - hf * hf);
    gb1f += dz1f;

    if (tid == 0) { xrL[d] = spinf; dz20L[d] = dz20; dz21L[d] = dz21; }

    z1 = fma((double)spinf, (double)w1row[d], z1);
  }
  __syncthreads();   // publish xrL / dz2L (incl. step 63)

  // ---------------- Output offsets (flat concat: WAV, x, gW1, gb1, gW2, gb2) --------
  const size_t XO  = (size_t)NS;                       // 2048
  const size_t GW1 = XO  + (size_t)NS * DD;            // 133120
  const size_t GB1 = GW1 + (size_t)NS * HH * DD;       // 33687552
  const size_t GW2 = GB1 + (size_t)NS * HH;            // 34211840
  const size_t GB2 = GW2 + (size_t)NS * 2 * HH;        // 35260416

  out[GW2 + (size_t)i * 2 * HH + tid]      = gw20;
  out[GW2 + (size_t)i * 2 * HH + HH + tid] = gw21;
  out[GB1 + (size_t)i * HH + tid]          = gb1f;
  if (tid == 0) {
    out[i] = wav;
    out[GB2 + (size_t)i * 2 + 0] = gb20;
    out[GB2 + (size_t)i * 2 + 1] = gb21;
  }
  if (tid < DD) out[XO + (size_t)i * DD + tid] = xrL[tid];

  // -------- Phase B: gW1 via f32 replay + prefix; coalesced via LDS transpose -------
  // gW1[h,j] = x_j * (gb1 - prefix_{d<=j} dz1[d,h]);  dz1 recomputed from the
  // block-uniform dz2 scalars and a barrier-free f32 replay of this thread's z1.
  const size_t gw1base = GW1 + (size_t)i * (HH * DD);
  float z1f  = b1f;
  float pref = 0.0f;
  const int g  = lane >> 4;    // 4 groups of 16 lanes
  const int jj = lane & 15;

  #pragma unroll
  for (int c = 0; c < 4; ++c) {
    #pragma unroll
    for (int r = 0; r < 16; ++r) {
      const int j = 16 * c + r;
      float hf2  = tanhf(z1f);
      float dz1r = (dz20L[j] * w20f + dz21L[j] * w21f) * (1.0f - hf2 * hf2);
      pref += dz1r;
      float xv = xrL[j];
      tbuf[wv][r][lane] = xv * (gb1f - pref);
      z1f = fmaf(xv, w1row[j], z1f);
    }
    __syncthreads();
    #pragma unroll
    for (int p2 = 0; p2 < 16; ++p2) {
      const int hp = 4 * p2 + g;   // h-offset within this wave's 64 rows
      out[gw1base + (size_t)(64 * wv + hp) * DD + 16 * c + jj] = tbuf[wv][jj][hp];
    }
    __syncthreads();   // WAR: tbuf reused next chunk
  }
}

extern "C" void kernel_launch(void* const* d_in, const int* in_sizes, int n_in,
                              void* d_out, int out_size, void* d_ws, size_t ws_size,
                              hipStream_t stream) {
  (void)in_sizes; (void)n_in; (void)out_size; (void)d_ws; (void)ws_size;
  const float* W1 = (const float*)d_in[0];
  const float* b1 = (const float*)d_in[1];
  const float* W2 = (const float*)d_in[2];
  const float* b2 = (const float*)d_in[3];
  float* out = (float*)d_out;

  // Host-side JAX key chain, PARTITIONABLE threefry split:
  // key(1) = (0,1). split(key): child i = threefry2x32(key, (0, i)).
  // key, sub = split(key) -> key = child 0, sub = child 1.
  SubKeys sk;
  uint32_t k0 = 0u, k1 = 1u;
  for (int d = 0; d < DD; ++d) {
    uint32_t n0, n1, s0, s1;
    tf2x32(k0, k1, 0u, 0u, &n0, &n1);   // child 0 -> next carry key
    tf2x32(k0, k1, 0u, 1u, &s0, &s1);   // child 1 -> sub key
    sk.a[d] = s0; sk.b[d] = s1;
    k0 = n0; k1 = n1;
  }

  QNADE_43473658970605_kernel<<<dim3(NS), dim3(HH), 0, stream>>>(W1, b1, W2, b2, out, sk);
}

// Round 10
// 126.490 us; speedup vs baseline: 3.3937x; 1.8143x over previous
//
#include <hip/hip_runtime.h>
#include <hip/hip_bf16.h>
#include <stdint.h>
#include <math.h>

#define NS 2048
#define DD 64
#define HH 256

// flat output offsets (WAV, x, gW1, gb1, gW2, gb2)
#define XO_OFF  ((size_t)NS)                      // 2048
#define GW1_OFF (XO_OFF + (size_t)NS * DD)        // 133120
#define GB1_OFF (GW1_OFF + (size_t)NS * HH * DD)  // 33687552
#define GW2_OFF (GB1_OFF + (size_t)NS * HH)       // 34211840
#define GB2_OFF (GW2_OFF + (size_t)NS * 2 * HH)   // 35260416

struct SubKeys { uint32_t a[DD]; uint32_t b[DD]; };

// JAX/Random123 threefry2x32, 20 rounds.
__host__ __device__ static inline void tf2x32(uint32_t k0, uint32_t k1,
                                              uint32_t x0, uint32_t x1,
                                              uint32_t* o0, uint32_t* o1) {
  uint32_t ks0 = k0, ks1 = k1, ks2 = k0 ^ k1 ^ 0x1BD11BDAu;
  x0 += ks0; x1 += ks1;
#define TFROT(r) { x0 += x1; x1 = (x1 << (r)) | (x1 >> (32 - (r))); x1 ^= x0; }
  TFROT(13) TFROT(15) TFROT(26) TFROT(6)  x0 += ks1; x1 += ks2 + 1u;
  TFROT(17) TFROT(29) TFROT(16) TFROT(24) x0 += ks2; x1 += ks0 + 2u;
  TFROT(13) TFROT(15) TFROT(26) TFROT(6)  x0 += ks0; x1 += ks1 + 3u;
  TFROT(17) TFROT(29) TFROT(16) TFROT(24) x0 += ks1; x1 += ks2 + 4u;
  TFROT(13) TFROT(15) TFROT(26) TFROT(6)  x0 += ks2; x1 += ks0 + 5u;
#undef TFROT
  *o0 = x0; *o1 = x1;
}

// ---- Kernel 0: W1 [256][64] -> W1T [64][256] in ws (lane-coalesced step loads) ----
__launch_bounds__(256)
__global__ void QNADE_w1t_kernel(const float* __restrict__ W1, float* __restrict__ W1T) {
  int idx = blockIdx.x * 256 + threadIdx.x;   // 0..16383
  int h = idx >> 6, d = idx & 63;
  W1T[d * 256 + h] = W1[idx];
}

// ---- Kernel A: sampling. One WAVE per sample, 4 hidden units per lane. ----
// No barriers, no LDS: u broadcast by shfl, spins in a reg bitmask, ONE f64
// butterfly per wave per step (1/4 the cross-lane work of block-per-sample).
__launch_bounds__(64)
__global__ void QNADE_sample_kernel(const float* __restrict__ W1T,
                                    const float* __restrict__ b1,
                                    const float* __restrict__ W2,
                                    const float* __restrict__ b2,
                                    float* __restrict__ out,
                                    SubKeys sk) {
  const int i    = blockIdx.x;       // sample
  const int lane = threadIdx.x;      // 0..63

  // This lane's per-step uniform (step index = lane), partitionable threefry:
  uint32_t o0, o1;
  tf2x32(sk.a[lane], sk.b[lane], 0u, (uint32_t)i, &o0, &o1);
  const float u_reg = __uint_as_float(0x3f800000u | ((o0 ^ o1) >> 9)) - 1.0f;

  double z1[4];  float w20f[4], w21f[4];  double w20d[4], w21d[4];
  float gw20[4] = {0,0,0,0}, gw21[4] = {0,0,0,0}, gb1a[4] = {0,0,0,0};
  #pragma unroll
  for (int k = 0; k < 4; ++k) {
    int h = lane + 64 * k;
    z1[k]   = (double)b1[h];
    w20f[k] = W2[h];        w21f[k] = W2[HH + h];
    w20d[k] = (double)w20f[k]; w21d[k] = (double)w21f[k];
  }
  const double b20d = (double)b2[0], b21d = (double)b2[1];
  float wav = 1.0f, gb20 = 0.0f, gb21 = 0.0f;
  unsigned long long smask = 0ull;

  #pragma unroll 2
  for (int d = 0; d < DD; ++d) {
    float w1v[4];
    #pragma unroll
    for (int k = 0; k < 4; ++k) w1v[k] = W1T[d * 256 + lane + 64 * k];  // coalesced

    float hf[4]; double p0 = 0.0, p1 = 0.0;
    #pragma unroll
    for (int k = 0; k < 4; ++k) {
      hf[k] = tanhf((float)z1[k]);              // f32 tanh (validated r8/r9)
      double hd = (double)hf[k];
      p0 = fma(hd, w20d[k], p0);
      p1 = fma(hd, w21d[k], p1);
    }
    #pragma unroll
    for (int m = 32; m >= 1; m >>= 1) {         // one f64 butterfly per wave
      p0 += __shfl_xor(p0, m, 64);
      p1 += __shfl_xor(p1, m, 64);
    }
    double s0 = p0 + b20d, s1 = p1 + b21d;
    double ss = s0 * s0 + s1 * s1;
    double pd = fmin(s0 * s0 / ss, 1.0);
    float  u  = __shfl(u_reg, d, 64);
    bool   bit = (double)u < pd;                // f64 decision, np-faithful
    float  spinf = bit ? 1.0f : -1.0f;
    if (bit) smask |= (1ull << d);

    // backward-local in f32 (wave-uniform scalars)
    float s0f = (float)s0, s1f = (float)s1;
    float nrmf = sqrtf(s0f * s0f + s1f * s1f);
    float psip = s0f / nrmf, psin = s1f / nrmf;
    float self = bit ? psip : psin;
    wav *= self;
    float gf = 1.0f / self;
    float dz20 = ((bit ? gf : 0.0f) - psip) / nrmf;
    float dz21 = ((bit ? 0.0f : gf) - psin) / nrmf;
    gb20 += dz20; gb21 += dz21;

    #pragma unroll
    for (int k = 0; k < 4; ++k) {
      gw20[k] += dz20 * hf[k];
      gw21[k] += dz21 * hf[k];
      float dz1k = (dz20 * w20f[k] + dz21 * w21f[k]) * (1.0f - hf[k] * hf[k]);
      gb1a[k] += dz1k;
      z1[k] = fma((double)spinf, (double)w1v[k], z1[k]);
    }

    // stash block-uniform dz2 scalars in sample's gW1 block head (B reads then overwrites)
    if (lane == 0) {
      out[GW1_OFF + (size_t)i * (HH * DD) + d]      = dz20;
      out[GW1_OFF + (size_t)i * (HH * DD) + DD + d] = dz21;
    }
  }

  // epilogue
  out[XO_OFF + (size_t)i * DD + lane] = ((smask >> lane) & 1ull) ? 1.0f : -1.0f;
  #pragma unroll
  for (int k = 0; k < 4; ++k) {
    int h = lane + 64 * k;
    out[GW2_OFF + (size_t)i * 2 * HH + h]      = gw20[k];
    out[GW2_OFF + (size_t)i * 2 * HH + HH + h] = gw21[k];
    out[GB1_OFF + (size_t)i * HH + h]          = gb1a[k];
  }
  if (lane == 0) {
    out[i] = wav;
    out[GB2_OFF + (size_t)i * 2 + 0] = gb20;
    out[GB2_OFF + (size_t)i * 2 + 1] = gb21;
  }
}

// ---- Kernel B: gW1 via f32 replay, full occupancy, coalesced transpose stores ----
__launch_bounds__(HH)
__global__ void QNADE_gw1_kernel(const float* __restrict__ W1T,
                                 const float* __restrict__ b1,
                                 const float* __restrict__ W2,
                                 float* __restrict__ out) {
  __shared__ float xrL[DD];
  __shared__ float dzL[2 * DD];
  __shared__ float tbuf[4][16][66];

  const int i = blockIdx.x, tid = threadIdx.x;
  const int lane = tid & 63, wv = tid >> 6;
  const size_t gw1base = GW1_OFF + (size_t)i * (HH * DD);

  if (tid < DD)                       xrL[tid] = out[XO_OFF + (size_t)i * DD + tid];
  else if (tid >= 64 && tid < 192)    dzL[tid - 64] = out[gw1base + (tid - 64)];
  __syncthreads();

  const float gb1f = out[GB1_OFF + (size_t)i * HH + tid];  // A's gb1 (final output too)
  const float w20f = W2[tid], w21f = W2[HH + tid];
  float z1f = b1[tid];
  float pref = 0.0f;
  const int g = lane >> 4, jj = lane & 15;

  #pragma unroll
  for (int c = 0; c < 4; ++c) {
    #pragma unroll
    for (int r = 0; r < 16; ++r) {
      const int j = 16 * c + r;
      float hf  = tanhf(z1f);
      float dz1 = (dzL[j] * w20f + dzL[DD + j] * w21f) * (1.0f - hf * hf);
      pref += dz1;
      float xv = xrL[j];
      tbuf[wv][r][lane] = xv * (gb1f - pref);      // suffix exclusive of j
      z1f = fmaf(xv, W1T[j * 256 + tid], z1f);     // coalesced W1T load
    }
    __syncthreads();
    #pragma unroll
    for (int p2 = 0; p2 < 16; ++p2) {
      const int hp = 4 * p2 + g;
      out[gw1base + (size_t)(64 * wv + hp) * DD + 16 * c + jj] = tbuf[wv][jj][hp];
    }
    __syncthreads();   // WAR on tbuf
  }
}

extern "C" void kernel_launch(void* const* d_in, const int* in_sizes, int n_in,
                              void* d_out, int out_size, void* d_ws, size_t ws_size,
                              hipStream_t stream) {
  (void)in_sizes; (void)n_in; (void)out_size; (void)ws_size;
  const float* W1 = (const float*)d_in[0];
  const float* b1 = (const float*)d_in[1];
  const float* W2 = (const float*)d_in[2];
  const float* b2 = (const float*)d_in[3];
  float* out = (float*)d_out;
  float* W1T = (float*)d_ws;   // 64 KB

  // Host-side JAX key chain, PARTITIONABLE threefry split:
  // key(1)=(0,1); child i = threefry2x32(key,(0,i)); key=child0, sub=child1.
  SubKeys sk;
  uint32_t k0 = 0u, k1 = 1u;
  for (int d = 0; d < DD; ++d) {
    uint32_t n0, n1, s0, s1;
    tf2x32(k0, k1, 0u, 0u, &n0, &n1);
    tf2x32(k0, k1, 0u, 1u, &s0, &s1);
    sk.a[d] = s0; sk.b[d] = s1;
    k0 = n0; k1 = n1;
  }

  QNADE_w1t_kernel<<<dim3(64), dim3(256), 0, stream>>>(W1, W1T);
  QNADE_sample_kernel<<<dim3(NS), dim3(64), 0, stream>>>(W1T, b1, W2, b2, out, sk);
  QNADE_gw1_kernel<<<dim3(NS), dim3(HH), 0, stream>>>(W1T, b1, W2, out);
}

// Round 11
// 113.514 us; speedup vs baseline: 3.7816x; 1.1143x over previous
//
#include <hip/hip_runtime.h>
#include <hip/hip_bf16.h>
#include <stdint.h>
#include <math.h>

#define NS 2048
#define DD 64
#define HH 256

// flat output offsets (WAV, x, gW1, gb1, gW2, gb2)
#define XO_OFF  ((size_t)NS)                      // 2048
#define GW1_OFF (XO_OFF + (size_t)NS * DD)        // 133120
#define GB1_OFF (GW1_OFF + (size_t)NS * HH * DD)  // 33687552
#define GW2_OFF (GB1_OFF + (size_t)NS * HH)       // 34211840
#define GB2_OFF (GW2_OFF + (size_t)NS * 2 * HH)   // 35260416

struct SubKeys { uint32_t a[DD]; uint32_t b[DD]; };

// JAX/Random123 threefry2x32, 20 rounds.
__host__ __device__ static inline void tf2x32(uint32_t k0, uint32_t k1,
                                              uint32_t x0, uint32_t x1,
                                              uint32_t* o0, uint32_t* o1) {
  uint32_t ks0 = k0, ks1 = k1, ks2 = k0 ^ k1 ^ 0x1BD11BDAu;
  x0 += ks0; x1 += ks1;
#define TFROT(r) { x0 += x1; x1 = (x1 << (r)) | (x1 >> (32 - (r))); x1 ^= x0; }
  TFROT(13) TFROT(15) TFROT(26) TFROT(6)  x0 += ks1; x1 += ks2 + 1u;
  TFROT(17) TFROT(29) TFROT(16) TFROT(24) x0 += ks2; x1 += ks0 + 2u;
  TFROT(13) TFROT(15) TFROT(26) TFROT(6)  x0 += ks0; x1 += ks1 + 3u;
  TFROT(17) TFROT(29) TFROT(16) TFROT(24) x0 += ks1; x1 += ks2 + 4u;
  TFROT(13) TFROT(15) TFROT(26) TFROT(6)  x0 += ks2; x1 += ks0 + 5u;
#undef TFROT
  *o0 = x0; *o1 = x1;
}

// ---- Kernel 0: W1 [256][64] -> W1T [64][256] in ws (lane-coalesced step loads) ----
__launch_bounds__(256)
__global__ void QNADE_w1t_kernel(const float* __restrict__ W1, float* __restrict__ W1T) {
  int idx = blockIdx.x * 256 + threadIdx.x;   // 0..16383
  int h = idx >> 6, d = idx & 63;
  W1T[d * 256 + h] = W1[idx];
}

// ---- Kernel A: sampling. One WAVE per sample, 4 hidden units per lane. ----
// Full f32: np-mimicking op sequence (sqrt, div, square, clip, compare).
// No barriers, no LDS: u broadcast by shfl, spins in a reg bitmask, ONE f32
// butterfly per wave per step.
__launch_bounds__(64)
__global__ void QNADE_sample_kernel(const float* __restrict__ W1T,
                                    const float* __restrict__ b1,
                                    const float* __restrict__ W2,
                                    const float* __restrict__ b2,
                                    float* __restrict__ out,
                                    SubKeys sk) {
  const int i    = blockIdx.x;       // sample
  const int lane = threadIdx.x;      // 0..63

  // This lane's per-step uniform (step index = lane), partitionable threefry:
  uint32_t o0, o1;
  tf2x32(sk.a[lane], sk.b[lane], 0u, (uint32_t)i, &o0, &o1);
  const float u_reg = __uint_as_float(0x3f800000u | ((o0 ^ o1) >> 9)) - 1.0f;

  float z1[4], w20f[4], w21f[4];
  float gw20[4] = {0,0,0,0}, gw21[4] = {0,0,0,0}, gb1a[4] = {0,0,0,0};
  #pragma unroll
  for (int k = 0; k < 4; ++k) {
    int h = lane + 64 * k;
    z1[k]   = b1[h];
    w20f[k] = W2[h];
    w21f[k] = W2[HH + h];
  }
  const float b20 = b2[0], b21 = b2[1];
  float wav = 1.0f, gb20 = 0.0f, gb21 = 0.0f;
  unsigned long long smask = 0ull;

  #pragma unroll 2
  for (int d = 0; d < DD; ++d) {
    float w1v[4];
    #pragma unroll
    for (int k = 0; k < 4; ++k) w1v[k] = W1T[d * 256 + lane + 64 * k];  // coalesced

    float hf[4]; float p0 = 0.0f, p1 = 0.0f;
    #pragma unroll
    for (int k = 0; k < 4; ++k) {
      hf[k] = tanhf(z1[k]);
      p0 = fmaf(hf[k], w20f[k], p0);
      p1 = fmaf(hf[k], w21f[k], p1);
    }
    #pragma unroll
    for (int m = 32; m >= 1; m >>= 1) {         // one f32 butterfly per wave
      p0 += __shfl_xor(p0, m, 64);
      p1 += __shfl_xor(p1, m, 64);
    }
    float s0 = p0 + b20, s1 = p1 + b21;

    // np-faithful f32 sequence: norm, divide, square, clip, compare
    float nrmf = sqrtf(s0 * s0 + s1 * s1);
    float psip = s0 / nrmf, psin = s1 / nrmf;
    float p    = fminf(psip * psip, 1.0f);
    float u    = __shfl(u_reg, d, 64);
    bool  bit  = u < p;
    float spinf = bit ? 1.0f : -1.0f;
    if (bit) smask |= (1ull << d);

    float self = bit ? psip : psin;
    wav *= self;
    float gf = 1.0f / self;
    float dz20 = ((bit ? gf : 0.0f) - psip) / nrmf;
    float dz21 = ((bit ? 0.0f : gf) - psin) / nrmf;
    gb20 += dz20; gb21 += dz21;

    #pragma unroll
    for (int k = 0; k < 4; ++k) {
      gw20[k] = fmaf(dz20, hf[k], gw20[k]);
      gw21[k] = fmaf(dz21, hf[k], gw21[k]);
      float dz1k = (dz20 * w20f[k] + dz21 * w21f[k]) * (1.0f - hf[k] * hf[k]);
      gb1a[k] += dz1k;
      z1[k] = fmaf(spinf, w1v[k], z1[k]);
    }

    // stash block-uniform dz2 scalars in sample's gW1 block head (B reads then overwrites)
    if (lane == 0) {
      out[GW1_OFF + (size_t)i * (HH * DD) + d]      = dz20;
      out[GW1_OFF + (size_t)i * (HH * DD) + DD + d] = dz21;
    }
  }

  // epilogue
  out[XO_OFF + (size_t)i * DD + lane] = ((smask >> lane) & 1ull) ? 1.0f : -1.0f;
  #pragma unroll
  for (int k = 0; k < 4; ++k) {
    int h = lane + 64 * k;
    out[GW2_OFF + (size_t)i * 2 * HH + h]      = gw20[k];
    out[GW2_OFF + (size_t)i * 2 * HH + HH + h] = gw21[k];
    out[GB1_OFF + (size_t)i * HH + h]          = gb1a[k];
  }
  if (lane == 0) {
    out[i] = wav;
    out[GB2_OFF + (size_t)i * 2 + 0] = gb20;
    out[GB2_OFF + (size_t)i * 2 + 1] = gb21;
  }
}

// ---- Kernel B: gW1 via f32 replay, full occupancy, float4 coalesced stores ----
__launch_bounds__(HH)
__global__ void QNADE_gw1_kernel(const float* __restrict__ W1T,
                                 const float* __restrict__ b1,
                                 const float* __restrict__ W2,
                                 float* __restrict__ out) {
  __shared__ float xrL[DD];
  __shared__ float dzL[2 * DD];
  __shared__ float tbuf[4][16][66];

  const int i = blockIdx.x, tid = threadIdx.x;
  const int lane = tid & 63, wv = tid >> 6;
  const size_t gw1base = GW1_OFF + (size_t)i * (HH * DD);

  if (tid < DD)                       xrL[tid] = out[XO_OFF + (size_t)i * DD + tid];
  else if (tid >= 64 && tid < 192)    dzL[tid - 64] = out[gw1base + (tid - 64)];
  __syncthreads();

  const float gb1f = out[GB1_OFF + (size_t)i * HH + tid];  // A's gb1
  const float w20f = W2[tid], w21f = W2[HH + tid];
  float z1f = b1[tid];
  float pref = 0.0f;
  const int q = lane & 3, rr = lane >> 2;   // store-phase decomposition

  #pragma unroll
  for (int c = 0; c < 4; ++c) {
    #pragma unroll
    for (int r = 0; r < 16; ++r) {
      const int j = 16 * c + r;
      float hf  = tanhf(z1f);
      float dz1 = (dzL[j] * w20f + dzL[DD + j] * w21f) * (1.0f - hf * hf);
      pref += dz1;
      float xv = xrL[j];
      tbuf[wv][r][lane] = xv * (gb1f - pref);      // suffix exclusive of j
      z1f = fmaf(xv, W1T[j * 256 + tid], z1f);     // coalesced W1T load
    }
    __syncthreads();
    // float4 stores: lane covers rows hp=16p+rr, col-quad q. 2-way LDS banked (free).
    #pragma unroll
    for (int p2 = 0; p2 < 4; ++p2) {
      const int hp = 16 * p2 + rr;
      float4 v;
      v.x = tbuf[wv][4 * q + 0][hp];
      v.y = tbuf[wv][4 * q + 1][hp];
      v.z = tbuf[wv][4 * q + 2][hp];
      v.w = tbuf[wv][4 * q + 3][hp];
      *(float4*)&out[gw1base + (size_t)(64 * wv + hp) * DD + 16 * c + 4 * q] = v;
    }
    __syncthreads();   // WAR on tbuf
  }
}

extern "C" void kernel_launch(void* const* d_in, const int* in_sizes, int n_in,
                              void* d_out, int out_size, void* d_ws, size_t ws_size,
                              hipStream_t stream) {
  (void)in_sizes; (void)n_in; (void)out_size; (void)ws_size;
  const float* W1 = (const float*)d_in[0];
  const float* b1 = (const float*)d_in[1];
  const float* W2 = (const float*)d_in[2];
  const float* b2 = (const float*)d_in[3];
  float* out = (float*)d_out;
  float* W1T = (float*)d_ws;   // 64 KB

  // Host-side JAX key chain, PARTITIONABLE threefry split:
  // key(1)=(0,1); child i = threefry2x32(key,(0,i)); key=child0, sub=child1.
  SubKeys sk;
  uint32_t k0 = 0u, k1 = 1u;
  for (int d = 0; d < DD; ++d) {
    uint32_t n0, n1, s0, s1;
    tf2x32(k0, k1, 0u, 0u, &n0, &n1);
    tf2x32(k0, k1, 0u, 1u, &s0, &s1);
    sk.a[d] = s0; sk.b[d] = s1;
    k0 = n0; k1 = n1;
  }

  QNADE_w1t_kernel<<<dim3(64), dim3(256), 0, stream>>>(W1, W1T);
  QNADE_sample_kernel<<<dim3(NS), dim3(64), 0, stream>>>(W1T, b1, W2, b2, out, sk);
  QNADE_gw1_kernel<<<dim3(NS), dim3(HH), 0, stream>>>(W1T, b1, W2, out);
}

// Round 12
// 106.289 us; speedup vs baseline: 4.0387x; 1.0680x over previous
//
#include <hip/hip_runtime.h>
#include <hip/hip_bf16.h>
#include <stdint.h>
#include <math.h>

#define NS 2048
#define DD 64
#define HH 256

// flat output offsets (WAV, x, gW1, gb1, gW2, gb2)
#define XO_OFF  ((size_t)NS)                      // 2048
#define GW1_OFF (XO_OFF + (size_t)NS * DD)        // 133120
#define GB1_OFF (GW1_OFF + (size_t)NS * HH * DD)  // 33687552
#define GW2_OFF (GB1_OFF + (size_t)NS * HH)       // 34211840
#define GB2_OFF (GW2_OFF + (size_t)NS * 2 * HH)   // 35260416

struct SubKeys { uint32_t a[DD]; uint32_t b[DD]; };

// JAX/Random123 threefry2x32, 20 rounds.
__host__ __device__ static inline void tf2x32(uint32_t k0, uint32_t k1,
                                              uint32_t x0, uint32_t x1,
                                              uint32_t* o0, uint32_t* o1) {
  uint32_t ks0 = k0, ks1 = k1, ks2 = k0 ^ k1 ^ 0x1BD11BDAu;
  x0 += ks0; x1 += ks1;
#define TFROT(r) { x0 += x1; x1 = (x1 << (r)) | (x1 >> (32 - (r))); x1 ^= x0; }
  TFROT(13) TFROT(15) TFROT(26) TFROT(6)  x0 += ks1; x1 += ks2 + 1u;
  TFROT(17) TFROT(29) TFROT(16) TFROT(24) x0 += ks2; x1 += ks0 + 2u;
  TFROT(13) TFROT(15) TFROT(26) TFROT(6)  x0 += ks0; x1 += ks1 + 3u;
  TFROT(17) TFROT(29) TFROT(16) TFROT(24) x0 += ks1; x1 += ks2 + 4u;
  TFROT(13) TFROT(15) TFROT(26) TFROT(6)  x0 += ks2; x1 += ks0 + 5u;
#undef TFROT
  *o0 = x0; *o1 = x1;
}

// 64-lane sum-reduce via DPP (VALU-speed, no LDS). Result in lane 63 -> readlane.
// Sequence: row_shr:1,2,4,8 then row_bcast:15, row_bcast:31 (classic GCN reduce).
__device__ static inline float wave_red_dpp(float x) {
#define DPPADD(ctrl) \
  x += __int_as_float(__builtin_amdgcn_update_dpp(0, __float_as_int(x), (ctrl), 0xf, 0xf, true))
  DPPADD(0x111);  // row_shr:1
  DPPADD(0x112);  // row_shr:2
  DPPADD(0x114);  // row_shr:4
  DPPADD(0x118);  // row_shr:8
  DPPADD(0x142);  // row_bcast:15
  DPPADD(0x143);  // row_bcast:31
#undef DPPADD
  return __int_as_float(__builtin_amdgcn_readlane(__float_as_int(x), 63));
}

// ---- Kernel 0: W1 [256][64] -> W1T [64][256] in ws (lane-coalesced step loads) ----
__launch_bounds__(256)
__global__ void QNADE_w1t_kernel(const float* __restrict__ W1, float* __restrict__ W1T) {
  int idx = blockIdx.x * 256 + threadIdx.x;   // 0..16383
  int h = idx >> 6, d = idx & 63;
  W1T[d * 256 + h] = W1[idx];
}

// ---- Kernel A: sampling. One WAVE per sample, 4 hidden units per lane. ----
// Full f32. DPP reduce (no LDS ops on the serial chain); u-transport via ballot.
__launch_bounds__(64)
__global__ void QNADE_sample_kernel(const float* __restrict__ W1T,
                                    const float* __restrict__ b1,
                                    const float* __restrict__ W2,
                                    const float* __restrict__ b2,
                                    float* __restrict__ out,
                                    SubKeys sk) {
  const int i    = blockIdx.x;       // sample
  const int lane = threadIdx.x;      // 0..63

  // This lane's per-step uniform (step index = lane), partitionable threefry:
  uint32_t o0, o1;
  tf2x32(sk.a[lane], sk.b[lane], 0u, (uint32_t)i, &o0, &o1);
  const float u_reg = __uint_as_float(0x3f800000u | ((o0 ^ o1) >> 9)) - 1.0f;

  float z1[4], w20f[4], w21f[4];
  float gw20[4] = {0,0,0,0}, gw21[4] = {0,0,0,0}, gb1a[4] = {0,0,0,0};
  #pragma unroll
  for (int k = 0; k < 4; ++k) {
    int h = lane + 64 * k;
    z1[k]   = b1[h];
    w20f[k] = W2[h];
    w21f[k] = W2[HH + h];
  }
  const float b20 = b2[0], b21 = b2[1];
  float wav = 1.0f, gb20 = 0.0f, gb21 = 0.0f;
  unsigned long long smask = 0ull;

  #pragma unroll 2
  for (int d = 0; d < DD; ++d) {
    float w1v[4];
    #pragma unroll
    for (int k = 0; k < 4; ++k) w1v[k] = W1T[d * 256 + lane + 64 * k];  // coalesced

    float hf[4]; float p0 = 0.0f, p1 = 0.0f;
    #pragma unroll
    for (int k = 0; k < 4; ++k) {
      hf[k] = tanhf(z1[k]);
      p0 = fmaf(hf[k], w20f[k], p0);
      p1 = fmaf(hf[k], w21f[k], p1);
    }
    float s0 = wave_red_dpp(p0) + b20;   // VALU cross-lane, no LDS
    float s1 = wave_red_dpp(p1) + b21;

    // np-faithful f32 sequence: norm, divide, square, clip, compare
    float nrmf = sqrtf(s0 * s0 + s1 * s1);
    float psip = s0 / nrmf, psin = s1 / nrmf;
    float p    = fminf(psip * psip, 1.0f);
    // u-transport: every lane compares ITS u (step=lane) vs uniform p; pick bit d.
    unsigned long long bal = __ballot(u_reg < p);
    bool  bit  = (bal >> d) & 1ull;
    float spinf = bit ? 1.0f : -1.0f;
    if (bit) smask |= (1ull << d);

    float self = bit ? psip : psin;
    wav *= self;
    float gf = 1.0f / self;
    float dz20 = ((bit ? gf : 0.0f) - psip) / nrmf;
    float dz21 = ((bit ? 0.0f : gf) - psin) / nrmf;
    gb20 += dz20; gb21 += dz21;

    #pragma unroll
    for (int k = 0; k < 4; ++k) {
      gw20[k] = fmaf(dz20, hf[k], gw20[k]);
      gw21[k] = fmaf(dz21, hf[k], gw21[k]);
      float dz1k = (dz20 * w20f[k] + dz21 * w21f[k]) * (1.0f - hf[k] * hf[k]);
      gb1a[k] += dz1k;
      z1[k] = fmaf(spinf, w1v[k], z1[k]);
    }

    // stash block-uniform dz2 scalars in sample's gW1 block head (B reads then overwrites)
    if (lane == 0) {
      out[GW1_OFF + (size_t)i * (HH * DD) + d]      = dz20;
      out[GW1_OFF + (size_t)i * (HH * DD) + DD + d] = dz21;
    }
  }

  // epilogue
  out[XO_OFF + (size_t)i * DD + lane] = ((smask >> lane) & 1ull) ? 1.0f : -1.0f;
  #pragma unroll
  for (int k = 0; k < 4; ++k) {
    int h = lane + 64 * k;
    out[GW2_OFF + (size_t)i * 2 * HH + h]      = gw20[k];
    out[GW2_OFF + (size_t)i * 2 * HH + HH + h] = gw21[k];
    out[GB1_OFF + (size_t)i * HH + h]          = gb1a[k];
  }
  if (lane == 0) {
    out[i] = wav;
    out[GB2_OFF + (size_t)i * 2 + 0] = gb20;
    out[GB2_OFF + (size_t)i * 2 + 1] = gb21;
  }
}

// ---- Kernel B: gW1 via f32 replay, full occupancy, float4 coalesced stores ----
__launch_bounds__(HH)
__global__ void QNADE_gw1_kernel(const float* __restrict__ W1T,
                                 const float* __restrict__ b1,
                                 const float* __restrict__ W2,
                                 float* __restrict__ out) {
  __shared__ float xrL[DD];
  __shared__ float dzL[2 * DD];
  __shared__ float tbuf[4][16][66];

  const int i = blockIdx.x, tid = threadIdx.x;
  const int lane = tid & 63, wv = tid >> 6;
  const size_t gw1base = GW1_OFF + (size_t)i * (HH * DD);

  if (tid < DD)                       xrL[tid] = out[XO_OFF + (size_t)i * DD + tid];
  else if (tid >= 64 && tid < 192)    dzL[tid - 64] = out[gw1base + (tid - 64)];
  __syncthreads();

  const float gb1f = out[GB1_OFF + (size_t)i * HH + tid];  // A's gb1
  const float w20f = W2[tid], w21f = W2[HH + tid];
  float z1f = b1[tid];
  float pref = 0.0f;
  const int q = lane & 3, rr = lane >> 2;   // store-phase decomposition

  #pragma unroll
  for (int c = 0; c < 4; ++c) {
    #pragma unroll
    for (int r = 0; r < 16; ++r) {
      const int j = 16 * c + r;
      float hf  = tanhf(z1f);
      float dz1 = (dzL[j] * w20f + dzL[DD + j] * w21f) * (1.0f - hf * hf);
      pref += dz1;
      float xv = xrL[j];
      tbuf[wv][r][lane] = xv * (gb1f - pref);      // suffix exclusive of j
      z1f = fmaf(xv, W1T[j * 256 + tid], z1f);     // coalesced W1T load
    }
    __syncthreads();
    // float4 stores: lane covers rows hp=16p+rr, col-quad q. 2-way LDS banked (free).
    #pragma unroll
    for (int p2 = 0; p2 < 4; ++p2) {
      const int hp = 16 * p2 + rr;
      float4 v;
      v.x = tbuf[wv][4 * q + 0][hp];
      v.y = tbuf[wv][4 * q + 1][hp];
      v.z = tbuf[wv][4 * q + 2][hp];
      v.w = tbuf[wv][4 * q + 3][hp];
      *(float4*)&out[gw1base + (size_t)(64 * wv + hp) * DD + 16 * c + 4 * q] = v;
    }
    __syncthreads();   // WAR on tbuf
  }
}

extern "C" void kernel_launch(void* const* d_in, const int* in_sizes, int n_in,
                              void* d_out, int out_size, void* d_ws, size_t ws_size,
                              hipStream_t stream) {
  (void)in_sizes; (void)n_in; (void)out_size; (void)ws_size;
  const float* W1 = (const float*)d_in[0];
  const float* b1 = (const float*)d_in[1];
  const float* W2 = (const float*)d_in[2];
  const float* b2 = (const float*)d_in[3];
  float* out = (float*)d_out;
  float* W1T = (float*)d_ws;   // 64 KB

  // Host-side JAX key chain, PARTITIONABLE threefry split:
  // key(1)=(0,1); child i = threefry2x32(key,(0,i)); key=child0, sub=child1.
  SubKeys sk;
  uint32_t k0 = 0u, k1 = 1u;
  for (int d = 0; d < DD; ++d) {
    uint32_t n0, n1, s0, s1;
    tf2x32(k0, k1, 0u, 0u, &n0, &n1);
    tf2x32(k0, k1, 0u, 1u, &s0, &s1);
    sk.a[d] = s0; sk.b[d] = s1;
    k0 = n0; k1 = n1;
  }

  QNADE_w1t_kernel<<<dim3(64), dim3(256), 0, stream>>>(W1, W1T);
  QNADE_sample_kernel<<<dim3(NS), dim3(64), 0, stream>>>(W1T, b1, W2, b2, out, sk);
  QNADE_gw1_kernel<<<dim3(NS), dim3(HH), 0, stream>>>(W1T, b1, W2, out);
}

// Round 13
// 78.217 us; speedup vs baseline: 5.4881x; 1.3589x over previous
//
#include <hip/hip_runtime.h>
#include <hip/hip_bf16.h>
#include <stdint.h>
#include <math.h>

#define NS 2048
#define DD 64
#define HH 256

// flat output offsets (WAV, x, gW1, gb1, gW2, gb2)
#define XO_OFF  ((size_t)NS)                      // 2048
#define GW1_OFF (XO_OFF + (size_t)NS * DD)        // 133120
#define GB1_OFF (GW1_OFF + (size_t)NS * HH * DD)  // 33687552
#define GW2_OFF (GB1_OFF + (size_t)NS * HH)       // 34211840
#define GB2_OFF (GW2_OFF + (size_t)NS * 2 * HH)   // 35260416

struct SubKeys { uint32_t a[DD]; uint32_t b[DD]; };

// JAX/Random123 threefry2x32, 20 rounds.
__host__ __device__ static inline void tf2x32(uint32_t k0, uint32_t k1,
                                              uint32_t x0, uint32_t x1,
                                              uint32_t* o0, uint32_t* o1) {
  uint32_t ks0 = k0, ks1 = k1, ks2 = k0 ^ k1 ^ 0x1BD11BDAu;
  x0 += ks0; x1 += ks1;
#define TFROT(r) { x0 += x1; x1 = (x1 << (r)) | (x1 >> (32 - (r))); x1 ^= x0; }
  TFROT(13) TFROT(15) TFROT(26) TFROT(6)  x0 += ks1; x1 += ks2 + 1u;
  TFROT(17) TFROT(29) TFROT(16) TFROT(24) x0 += ks2; x1 += ks0 + 2u;
  TFROT(13) TFROT(15) TFROT(26) TFROT(6)  x0 += ks0; x1 += ks1 + 3u;
  TFROT(17) TFROT(29) TFROT(16) TFROT(24) x0 += ks1; x1 += ks2 + 4u;
  TFROT(13) TFROT(15) TFROT(26) TFROT(6)  x0 += ks2; x1 += ks0 + 5u;
#undef TFROT
  *o0 = x0; *o1 = x1;
}

// Branchless f32 tanh: 1 - 2/(e^{2x}+1). ~1.5 ulp; saturates correctly both ends.
// z1 range here is |x| <~ 10 -> no overflow/denormal issues for raw v_exp_f32.
__device__ static inline float fast_tanh(float x) {
  float t = __builtin_amdgcn_exp2f(x * 2.88539008177792681472f);  // e^{2x}
  return 1.0f - 2.0f / (t + 1.0f);   // IEEE div keeps error ~1 ulp
}

// 64-lane sum-reduce via DPP (VALU-speed, no LDS). Result broadcast via readlane 63.
__device__ static inline float wave_red_dpp(float x) {
#define DPPADD(ctrl) \
  x += __int_as_float(__builtin_amdgcn_update_dpp(0, __float_as_int(x), (ctrl), 0xf, 0xf, true))
  DPPADD(0x111);  // row_shr:1
  DPPADD(0x112);  // row_shr:2
  DPPADD(0x114);  // row_shr:4
  DPPADD(0x118);  // row_shr:8
  DPPADD(0x142);  // row_bcast:15
  DPPADD(0x143);  // row_bcast:31
#undef DPPADD
  return __int_as_float(__builtin_amdgcn_readlane(__float_as_int(x), 63));
}

// ---- Kernel 0: build W1T [64][256] (h-major) and W1Q [64][64][4] (lane-packed) ----
__launch_bounds__(256)
__global__ void QNADE_w1t_kernel(const float* __restrict__ W1,
                                 float* __restrict__ W1T,
                                 float* __restrict__ W1Q) {
  int idx = blockIdx.x * 256 + threadIdx.x;   // 0..16383
  int h = idx >> 6, d = idx & 63;
  float v = W1[idx];
  W1T[d * 256 + h] = v;                              // B-phase: coalesced per-h
  W1Q[d * 256 + (h & 63) * 4 + (h >> 6)] = v;        // A-phase: dwordx4 per lane
}

// ---- Fused kernel: wave (i&3) samples; all 4 waves then build gW1 from LDS ----
__launch_bounds__(256, 8)   // 8 waves/EU -> 8 blocks/CU (LDS 18.3KB/block)
__global__ void QNADE_fused_kernel(const float* __restrict__ W1T,
                                   const float* __restrict__ W1Q,
                                   const float* __restrict__ b1,
                                   const float* __restrict__ W2,
                                   const float* __restrict__ b2,
                                   float* __restrict__ out,
                                   SubKeys sk) {
  __shared__ float xrL[DD];           // spins
  __shared__ float dzL[2 * DD];       // per-step dz2 scalars
  __shared__ float gbL[HH];           // gb1 per hidden unit
  __shared__ float tbuf[4][16][66];   // per-wave transpose buffer

  const int i    = blockIdx.x;        // sample
  const int tid  = threadIdx.x;
  const int lane = tid & 63;
  const int wv   = tid >> 6;
  const int sw   = i & 3;             // sampling wave id (spread across SIMDs)

  // Hoisted loads used by the gW1 phase (all waves; hides under sampling phase).
  const float w20h = W2[tid];
  const float w21h = W2[HH + tid];
  const float b1h  = b1[tid];

  if (wv == sw) {
    // ---------------- Phase A: sampling (one wave), 4 hidden units/lane ----------
    uint32_t o0, o1;
    tf2x32(sk.a[lane], sk.b[lane], 0u, (uint32_t)i, &o0, &o1);
    const float u_reg = __uint_as_float(0x3f800000u | ((o0 ^ o1) >> 9)) - 1.0f;

    float z1[4], w20f[4], w21f[4];
    float gw20[4] = {0,0,0,0}, gw21[4] = {0,0,0,0}, gb1a[4] = {0,0,0,0};
    #pragma unroll
    for (int k = 0; k < 4; ++k) {
      int h = lane + 64 * k;
      z1[k]   = b1[h];
      w20f[k] = W2[h];
      w21f[k] = W2[HH + h];
    }
    const float b20 = b2[0], b21 = b2[1];
    float wav = 1.0f, gb20 = 0.0f, gb21 = 0.0f;
    unsigned long long smask = 0ull;

    #pragma unroll 2
    for (int d = 0; d < DD; ++d) {
      const float4 w4 = *(const float4*)&W1Q[d * 256 + lane * 4];  // 1 dwordx4

      float hf[4]; float p0 = 0.0f, p1 = 0.0f;
      #pragma unroll
      for (int k = 0; k < 4; ++k) {
        hf[k] = fast_tanh(z1[k]);
        p0 = fmaf(hf[k], w20f[k], p0);
        p1 = fmaf(hf[k], w21f[k], p1);
      }
      float s0 = wave_red_dpp(p0) + b20;
      float s1 = wave_red_dpp(p1) + b21;

      // decision path unchanged: sqrt, exact div, square, clip, compare
      float nrmf = sqrtf(s0 * s0 + s1 * s1);
      float psip = s0 / nrmf;
      float p    = fminf(psip * psip, 1.0f);
      unsigned long long bal = __ballot(u_reg < p);
      bool  bit  = (bal >> d) & 1ull;
      float spinf = bit ? 1.0f : -1.0f;
      if (bit) smask |= (1ull << d);

      // backward-local (off decision path; rcp-based, ~1ulp)
      float rn   = 1.0f / nrmf;
      float psin = s1 * rn;
      float self = bit ? psip : psin;
      wav *= self;
      float gf   = 1.0f / self;
      float dz20 = ((bit ? gf : 0.0f) - psip) * rn;
      float dz21 = ((bit ? 0.0f : gf) - psin) * rn;
      gb20 += dz20; gb21 += dz21;

      #pragma unroll
      for (int k = 0; k < 4; ++k) {
        gw20[k] = fmaf(dz20, hf[k], gw20[k]);
        gw21[k] = fmaf(dz21, hf[k], gw21[k]);
        float dz1k = (dz20 * w20f[k] + dz21 * w21f[k]) * (1.0f - hf[k] * hf[k]);
        gb1a[k] += dz1k;
        float wk = (k == 0) ? w4.x : (k == 1) ? w4.y : (k == 2) ? w4.z : w4.w;
        z1[k] = fmaf(spinf, wk, z1[k]);
      }

      if (lane == 0) { xrL[d] = spinf; dzL[d] = dz20; dzL[DD + d] = dz21; }
    }

    // epilogue (sampling wave): publish to LDS + global small outputs
    out[XO_OFF + (size_t)i * DD + lane] = ((smask >> lane) & 1ull) ? 1.0f : -1.0f;
    #pragma unroll
    for (int k = 0; k < 4; ++k) {
      int h = lane + 64 * k;
      gbL[h] = gb1a[k];
      out[GW2_OFF + (size_t)i * 2 * HH + h]      = gw20[k];
      out[GW2_OFF + (size_t)i * 2 * HH + HH + h] = gw21[k];
      out[GB1_OFF + (size_t)i * HH + h]          = gb1a[k];
    }
    if (lane == 0) {
      out[i] = wav;
      out[GB2_OFF + (size_t)i * 2 + 0] = gb20;
      out[GB2_OFF + (size_t)i * 2 + 1] = gb21;
    }
  }
  __syncthreads();   // xrL, dzL, gbL visible to all waves

  // ---------------- Phase B: gW1 via f32 replay (all 4 waves) ----------------------
  const size_t gw1base = GW1_OFF + (size_t)i * (HH * DD);
  const float gb1f = gbL[tid];
  float z1f = b1h;
  float pref = 0.0f;
  const int q = lane & 3, rr = lane >> 2;

  #pragma unroll
  for (int c = 0; c < 4; ++c) {
    #pragma unroll
    for (int r = 0; r < 16; ++r) {
      const int j = 16 * c + r;
      float hf  = fast_tanh(z1f);
      float dz1 = (dzL[j] * w20h + dzL[DD + j] * w21h) * (1.0f - hf * hf);
      pref += dz1;
      float xv = xrL[j];
      tbuf[wv][r][lane] = xv * (gb1f - pref);      // suffix exclusive of j
      z1f = fmaf(xv, W1T[j * 256 + tid], z1f);     // coalesced
    }
    __syncthreads();
    #pragma unroll
    for (int p2 = 0; p2 < 4; ++p2) {
      const int hp = 16 * p2 + rr;
      float4 v;
      v.x = tbuf[wv][4 * q + 0][hp];
      v.y = tbuf[wv][4 * q + 1][hp];
      v.z = tbuf[wv][4 * q + 2][hp];
      v.w = tbuf[wv][4 * q + 3][hp];
      *(float4*)&out[gw1base + (size_t)(64 * wv + hp) * DD + 16 * c + 4 * q] = v;
    }
    __syncthreads();   // WAR on tbuf
  }
}

extern "C" void kernel_launch(void* const* d_in, const int* in_sizes, int n_in,
                              void* d_out, int out_size, void* d_ws, size_t ws_size,
                              hipStream_t stream) {
  (void)in_sizes; (void)n_in; (void)out_size; (void)ws_size;
  const float* W1 = (const float*)d_in[0];
  const float* b1 = (const float*)d_in[1];
  const float* W2 = (const float*)d_in[2];
  const float* b2 = (const float*)d_in[3];
  float* out = (float*)d_out;
  float* W1T = (float*)d_ws;            // 64 KB
  float* W1Q = (float*)d_ws + HH * DD;  // 64 KB

  // Host-side JAX key chain, PARTITIONABLE threefry split:
  // key(1)=(0,1); child i = threefry2x32(key,(0,i)); key=child0, sub=child1.
  SubKeys sk;
  uint32_t k0 = 0u, k1 = 1u;
  for (int d = 0; d < DD; ++d) {
    uint32_t n0, n1, s0, s1;
    tf2x32(k0, k1, 0u, 0u, &n0, &n1);
    tf2x32(k0, k1, 0u, 1u, &s0, &s1);
    sk.a[d] = s0; sk.b[d] = s1;
    k0 = n0; k1 = n1;
  }

  QNADE_w1t_kernel<<<dim3(64), dim3(256), 0, stream>>>(W1, W1T, W1Q);
  QNADE_fused_kernel<<<dim3(NS), dim3(256), 0, stream>>>(W1T, W1Q, b1, W2, b2, out, sk);
}